// Round 12
// baseline (343.313 us; speedup 1.0000x reference)
//
#include <hip/hip_runtime.h>

// Conv1d via implicit GEMM on MFMA f16.
// out[b,co,t] = bias[co] + sum_{ci,m} w[co,ci,m] * x[b,ci,t-32+m], t in [0,4032)
// R10 (3rd submit; benches never ran — acquisition timeouts):
//      LDS-BW fix. LDS carries only X ([chunk][row], conflict-free).
//      W (A-frags) read global->VGPR, 1-body register ping-pong, compiler
//      vmcnt. One bare s_barrier per body (phase cohesion for L1 W-sharing).
//      k=64 body as R8.

typedef _Float16 f16;
typedef _Float16 f16x8 __attribute__((ext_vector_type(8)));
typedef float f32x4 __attribute__((ext_vector_type(4)));

#define NB   16
#define CI   128
#define CO   128
#define LIN  4096
#define KW   129
#define TOUT 4032
#define UPAD 4224                 // xT rows per (b, p, chunk)
#define XT_BYTES ((size_t)NB * 2 * 8 * UPAD * 16)   // 17,301,504

__device__ __forceinline__ void gld16(void* lds, const void* g) {
    __builtin_amdgcn_global_load_lds(
        (const __attribute__((address_space(1))) unsigned int*)g,
        (__attribute__((address_space(3))) unsigned int*)lds,
        16, 0, 0);
}

// ---- pre-pass 1: x (f32, [b][ci][l]) -> xt2 (f16, [b][p][c8][u] 16B units) --------
// u = l + 32; rows u<32 and u>=4128 are zero. Unit (b,p,c,u) holds
// x[b][ci = p*64 + c*8 .. +8][u-32] as 8 f16.
__global__ __launch_bounds__(256) void xt_prep(const float* __restrict__ x,
                                               f16* __restrict__ xt) {
    __shared__ float tile[128][33];           // [ci][lcol], +1 pad
    const int b  = blockIdx.y;
    const int u0 = blockIdx.x * 32;
    const int l0 = u0 - 32;
    const int tid = threadIdx.x;
    const int col = tid & 31;
    const int cib = tid >> 5;                 // 0..7
#pragma unroll
    for (int r = 0; r < 16; ++r) {
        int ci = cib + r * 8;
        int l  = l0 + col;
        float v = 0.f;
        if (l >= 0 && l < LIN) v = x[((size_t)b * CI + ci) * LIN + l];
        tile[ci][col] = v;
    }
    __syncthreads();
#pragma unroll
    for (int it = 0; it < 2; ++it) {
        int idx   = tid + it * 256;           // 0..511 = 16 chunks * 32 rows
        int chunk = idx >> 5;                 // 0..15  (= p*8 + c)
        int ur    = idx & 31;
        f16x8 v;
#pragma unroll
        for (int j = 0; j < 8; ++j) v[j] = (f16)tile[chunk * 8 + j][ur];
        size_t unit = ((size_t)b * 16 + chunk) * UPAD + (u0 + ur);
        *(f16x8*)(&xt[unit * 8]) = v;
    }
}

// ---- pre-pass 2: w (f32, [co][ci][m]) -> wt2 (f16, [kk][c4][co] 16B units) -------
// kk = m*4 + cic. Unit (kk,c,co) holds w[co][ci=(kk&3)*32 + c*8 .. +8][kk>>2].
__global__ __launch_bounds__(256) void wt_prep(const float* __restrict__ w,
                                               f16* __restrict__ wt) {
    __shared__ float tile[32][132];           // [ci_local][m], padded
    const int cic = blockIdx.x;               // 0..3
    const int co  = blockIdx.y;               // 0..127
    const int ci0 = cic * 32;
    const int tid = threadIdx.x;
    for (int it = 0; it < 17; ++it) {
        int idx = tid + it * 256;
        if (idx < 32 * 129) {
            int i = idx / 129;
            int m = idx - i * 129;
            tile[i][m] = w[(size_t)co * (CI * KW) + (size_t)(ci0 + i) * KW + m];
        }
    }
    __syncthreads();
    for (int it = 0; it < 3; ++it) {
        int idx = tid + it * 256;
        if (idx < 129 * 4) {
            int m = idx >> 2;
            int c = idx & 3;
            int kk = m * 4 + cic;
            f16x8 v;
#pragma unroll
            for (int j = 0; j < 8; ++j) v[j] = (f16)tile[c * 8 + j][m];
            *(f16x8*)(&wt[(size_t)kk * 4096 + c * 1024 + co * 8]) = v;
        }
    }
}

// ---- main kernel: 128co x 128t per block, 4 waves of 64x64, k=64 per body --------
// LDS: X tile only, [8 chunks][256 rows][16B] = 32 KB.
__global__ __launch_bounds__(256, 2) void conv_main(
    const f16* __restrict__ xt, const f16* __restrict__ wt,
    const float* __restrict__ bias, float* __restrict__ out)
{
    extern __shared__ char smem[];
    const int tid  = threadIdx.x;
    const int lane = tid & 63;
    const int wid  = tid >> 6;
    const int l15  = lane & 15;
    const int l4   = lane >> 4;
    const int wco  = (wid >> 1) << 6;     // 0 / 64
    const int wtt  = (wid & 1) << 6;      // 0 / 64

    const int tt = blockIdx.x;            // 0..31 (t-tile)
    const int b  = blockIdx.y;            // 0..15
    const int u0 = tt << 7;

    const char* wbase = (const char*)wt;
    // A-frag global address: wbase + (4t+pbase+q)*8192 + alane + ct*256
    const int alane = l4 * 2048 + wco * 16 + l15 * 16;
    // B-frag LDS address: smem + l4*4096 + (wtt+l15)*16 + t*16 + q*16384 + st*256
    const int blane = l4 * 4096 + (wtt + l15) * 16;

    f32x4 acc[4][4];
#pragma unroll
    for (int i = 0; i < 4; ++i)
#pragma unroll
        for (int j = 0; j < 4; ++j)
            acc[i][j] = (f32x4){0.f, 0.f, 0.f, 0.f};

    f16x8 afA[2][4], bfA[2][4], afB[2][4], bfB[2][4];

    for (int p = 0; p < 2; ++p) {         // ci-halves
        const int pbase = 2 * p;

        if (p) {                          // own LDS reads drained, then all arrive
            asm volatile("s_waitcnt lgkmcnt(0)" ::: "memory");
            __builtin_amdgcn_s_barrier();
        }
        // stage X half: chunk i rows u0..u0+255 -> LDS [i][row]
        const char* xph = (const char*)xt +
            (((size_t)b * 16 + p * 8) * UPAD + u0) * 16;
#pragma unroll
        for (int i = 0; i < 8; ++i)
            gld16(smem + tid * 16 + i * 4096, xph + (size_t)i * (UPAD * 16) + tid * 16);

        // prologue A-frags for t=0 (global -> regs, overlaps X DMA)
        {
            const char* a0 = wbase + (size_t)pbase * 8192 + alane;
#pragma unroll
            for (int q = 0; q < 2; ++q)
#pragma unroll
                for (int ct = 0; ct < 4; ++ct)
                    afA[q][ct] = *(const f16x8*)(a0 + q * 8192 + ct * 256);
        }
        asm volatile("s_waitcnt vmcnt(0)" ::: "memory");  // X + afA resident
        __builtin_amdgcn_s_barrier();

        // prologue B-frags for t=0
#pragma unroll
        for (int q = 0; q < 2; ++q)
#pragma unroll
            for (int st = 0; st < 4; ++st)
                bfA[q][st] = *(const f16x8*)(smem + blane + q * 16384 + st * 256);

        // body(t): bare barrier; load frags t+1 (af global, bf LDS); MFMA t.
        auto body = [&](int t, f16x8 (&afC)[2][4], f16x8 (&bfC)[2][4],
                               f16x8 (&afN)[2][4], f16x8 (&bfN)[2][4]) {
            __builtin_amdgcn_s_barrier();           // phase cohesion only
            if (t + 1 <= 128) {
                const int tn = t + 1;
                const char* an = wbase + (size_t)(4 * tn + pbase) * 8192 + alane;
                const char* bn = smem + blane + tn * 16;
#pragma unroll
                for (int q = 0; q < 2; ++q)
#pragma unroll
                    for (int ct = 0; ct < 4; ++ct)
                        afN[q][ct] = *(const f16x8*)(an + q * 8192 + ct * 256);
#pragma unroll
                for (int q = 0; q < 2; ++q)
#pragma unroll
                    for (int st = 0; st < 4; ++st)
                        bfN[q][st] = *(const f16x8*)(bn + q * 16384 + st * 256);
            }
#pragma unroll
            for (int q = 0; q < 2; ++q)
#pragma unroll
                for (int ct = 0; ct < 4; ++ct)
#pragma unroll
                    for (int st = 0; st < 4; ++st)
                        acc[ct][st] = __builtin_amdgcn_mfma_f32_16x16x32_f16(
                            afC[q][ct], bfC[q][st], acc[ct][st], 0, 0, 0);
        };

        for (int t2 = 0; t2 < 128; t2 += 2) {
            body(t2,     afA, bfA, afB, bfB);
            body(t2 + 1, afB, bfB, afA, bfA);
        }
        body(128, afA, bfA, afB, bfB);    // tail (loads nothing)
    }

    // epilogue: D[row=co_local][col=t_local]; row=(l>>4)*4+reg, col=l&15
#pragma unroll
    for (int ct = 0; ct < 4; ++ct) {
#pragma unroll
        for (int r = 0; r < 4; ++r) {
            int co = wco + ct * 16 + l4 * 4 + r;
            float bv = bias[co];
            float* orow = out + ((size_t)b * CO + co) * TOUT;
#pragma unroll
            for (int st = 0; st < 4; ++st) {
                int t = u0 + wtt + st * 16 + l15;
                if (t < TOUT) orow[t] = acc[ct][st][r] + bv;
            }
        }
    }
}

extern "C" void kernel_launch(void* const* d_in, const int* in_sizes, int n_in,
                              void* d_out, int out_size, void* d_ws, size_t ws_size,
                              hipStream_t stream) {
    const float* x    = (const float*)d_in[0];
    const float* w    = (const float*)d_in[1];
    const float* bias = (const float*)d_in[2];
    float* out = (float*)d_out;

    f16* xt = (f16*)d_ws;                              // 17,301,504 B
    f16* wt = (f16*)((char*)d_ws + XT_BYTES);          //  4,227,072 B

    xt_prep<<<dim3(UPAD / 32, NB), 256, 0, stream>>>(x, xt);
    wt_prep<<<dim3(4, CO), 256, 0, stream>>>(w, wt);
    conv_main<<<dim3(32, NB), 256, 32768, stream>>>(xt, wt, bias, out);
}